// Round 1
// baseline (300.987 us; speedup 1.0000x reference)
//
#include <hip/hip_runtime.h>
#include <math.h>

// HBV model RHS: elementwise over B=2,000,000 rows.
// Inputs (dict order):
//   d_in[0] = y            (B,5)   float32   in_sizes[0] = 5B
//   d_in[1] = theta        (14,)   float32
//   d_in[2] = climate_data (8,B,3) float32
//   d_in[3] = delta_t      scalar  float32
//   d_in[4] = t            scalar  int32
// Output: concat[ dS (B,5), fluxes (B,12) ] float32, out_size = 17B

__global__ __launch_bounds__(256) void hbv_rhs_kernel(
    const float* __restrict__ y,
    const float* __restrict__ theta,
    const float* __restrict__ climate,
    const float* __restrict__ dt_ptr,
    const int* __restrict__ t_ptr,
    float* __restrict__ dS,
    float* __restrict__ fluxes,
    int B)
{
    int i = blockIdx.x * blockDim.x + threadIdx.x;
    if (i >= B) return;

    // Broadcast scalars (uniform across wave; served from L1/L2).
    const float tt    = theta[0];
    const float tti   = theta[1];
    const float ttm   = theta[2];
    const float cfr   = theta[3];
    const float cfmax = theta[4];
    const float whc   = theta[5];
    const float cflux = theta[6];
    const float fc    = theta[7];
    const float lp    = theta[8];
    const float beta  = theta[9];
    const float k0    = theta[10];
    const float alpha = theta[11];
    const float perc  = theta[12];
    const float k1    = theta[13];
    const float dt    = dt_ptr[0];
    const int   t     = t_ptr[0];

    const float* __restrict__ ct = climate + (size_t)t * (size_t)B * 3u;

    // Per-row loads (strided but dense per wave).
    const size_t yb = (size_t)i * 5u;
    const float S1 = y[yb + 0];
    const float S2 = y[yb + 1];
    const float S3 = y[yb + 2];
    const float S4 = y[yb + 3];
    const float S5 = y[yb + 4];

    const size_t cb = (size_t)i * 3u;
    const float P  = ct[cb + 0];
    const float Ep = ct[cb + 1];
    const float T  = ct[cb + 2];

    const float zero = 0.0f;

    const float flux_sf   = fminf(P, fmaxf(zero, P * (tt + 0.5f * tti - T) / tti));
    const float flux_refr = fmaxf(fminf(cfr * cfmax * (ttm - T), S2 / dt), zero);
    const float flux_melt = fmaxf(fminf(cfmax * (T - ttm), S1 / dt), zero);
    const float flux_rf   = fminf(P, fmaxf(zero, P * (T - (tt - 0.5f * tti)) / tti));

    const float r = 0.01f, e = 5.0f;
    const float Smax_raw = whc * S1;
    const float Smax     = fmaxf(Smax_raw, zero);
    const float logistic = 1.0f / (1.0f + expf((S2 - Smax + r * e * Smax) / fmaxf(r, r * Smax)));
    const float flux_in  = (flux_rf + flux_melt) * (1.0f - logistic);
    const float flux_se  = fmaxf((S2 - Smax_raw) / dt, zero);
    const float flux_cf  = fminf(cflux * (1.0f - S3 / fc), S4 / dt);
    const float flux_ea  = fminf(fminf(S3 / (lp * fc) * Ep, Ep), S3 / dt);
    const float flux_r   = (flux_in + flux_se) * powf(fmaxf(S3, zero) / fc, beta);
    const float flux_q0  = fminf(k0 * powf(fmaxf(S4, zero), 1.0f + alpha), fmaxf(S4 / dt, zero));
    const float flux_perc = fminf(perc, S4 / dt);
    const float flux_q1  = k1 * S5;

    // dS (B,5): scalar stores (20B row stride; dense per wave).
    const size_t db = (size_t)i * 5u;
    dS[db + 0] = flux_sf + flux_refr - flux_melt;
    dS[db + 1] = flux_rf + flux_melt - flux_refr - flux_in - flux_se;
    dS[db + 2] = flux_in + flux_se + flux_cf - flux_ea - flux_r;
    dS[db + 3] = flux_r - flux_cf - flux_q0 - flux_perc;
    dS[db + 4] = flux_perc - flux_q1;

    // fluxes (B,12): each row is 48B, 16B-aligned -> 3x float4 stores.
    float4* __restrict__ frow = (float4*)(fluxes + (size_t)i * 12u);
    frow[0] = make_float4(flux_sf, flux_refr, flux_melt, flux_rf);
    frow[1] = make_float4(flux_in, flux_se, flux_cf, flux_ea);
    frow[2] = make_float4(flux_r, flux_q0, flux_perc, flux_q1);
}

extern "C" void kernel_launch(void* const* d_in, const int* in_sizes, int n_in,
                              void* d_out, int out_size, void* d_ws, size_t ws_size,
                              hipStream_t stream) {
    const float* y       = (const float*)d_in[0];
    const float* theta   = (const float*)d_in[1];
    const float* climate = (const float*)d_in[2];
    const float* dt_ptr  = (const float*)d_in[3];
    const int*   t_ptr   = (const int*)d_in[4];

    const int B = in_sizes[0] / 5;

    float* dS     = (float*)d_out;            // B*5
    float* fluxes = (float*)d_out + (size_t)B * 5u;  // B*12

    const int block = 256;
    const int grid  = (B + block - 1) / block;
    hbv_rhs_kernel<<<grid, block, 0, stream>>>(y, theta, climate, dt_ptr, t_ptr,
                                               dS, fluxes, B);
}

// Round 2
// 295.327 us; speedup vs baseline: 1.0192x; 1.0192x over previous
//
#include <hip/hip_runtime.h>
#include <math.h>

// HBV model RHS: elementwise over B=2,000,000 rows.
// Inputs (dict order):
//   d_in[0] = y            (B,5)   float32   in_sizes[0] = 5B
//   d_in[1] = theta        (14,)   float32
//   d_in[2] = climate_data (8,B,3) float32
//   d_in[3] = delta_t      scalar  float32
//   d_in[4] = t            scalar  int32
// Output: concat[ dS (B,5), fluxes (B,12) ] float32, out_size = 17B
//
// R1: all global traffic staged through LDS so every global access is a
// coalesced float4 (lane i -> 16B at base+16i). Row strides 5/3/5/12 live
// only in LDS, where gcd(stride,32)∈{1,4} keeps conflicts free/cheap.

#define BLOCK 256

__global__ __launch_bounds__(BLOCK) void hbv_rhs_kernel(
    const float* __restrict__ y,
    const float* __restrict__ theta,
    const float* __restrict__ climate,
    const float* __restrict__ dt_ptr,
    const int* __restrict__ t_ptr,
    float* __restrict__ dS,
    float* __restrict__ fluxes,
    int B)
{
    __shared__ float lds_y[BLOCK * 5];
    __shared__ float lds_c[BLOCK * 3];
    __shared__ float lds_d[BLOCK * 5];
    __shared__ float lds_f[BLOCK * 12];

    const int tid  = threadIdx.x;
    const int base = blockIdx.x * BLOCK;
    if (base >= B) return;
    const int nrows = min(BLOCK, B - base);

    const float dt = dt_ptr[0];
    const int   t  = t_ptr[0];
    const float* __restrict__ ct = climate + (size_t)t * (size_t)B * 3u;

    // ---- Phase 1: coalesced global -> LDS (float4 main, dword tail) ----
    const float* __restrict__ yb = y  + (size_t)base * 5u;   // 5120B-aligned per block
    const float* __restrict__ cb = ct + (size_t)base * 3u;   // 3072B-aligned per block
    const int ny = nrows * 5, nc = nrows * 3;
    const int ny4 = ny >> 2, nc4 = nc >> 2;
    for (int k = tid; k < ny4; k += BLOCK)
        ((float4*)lds_y)[k] = ((const float4*)yb)[k];
    for (int k = ny4 * 4 + tid; k < ny; k += BLOCK)
        lds_y[k] = yb[k];
    for (int k = tid; k < nc4; k += BLOCK)
        ((float4*)lds_c)[k] = ((const float4*)cb)[k];
    for (int k = nc4 * 4 + tid; k < nc; k += BLOCK)
        lds_c[k] = cb[k];

    // Broadcast scalars (uniform).
    const float tt    = theta[0];
    const float tti   = theta[1];
    const float ttm   = theta[2];
    const float cfr   = theta[3];
    const float cfmax = theta[4];
    const float whc   = theta[5];
    const float cflux = theta[6];
    const float fc    = theta[7];
    const float lp    = theta[8];
    const float beta  = theta[9];
    const float k0    = theta[10];
    const float alpha = theta[11];
    const float perc  = theta[12];
    const float k1    = theta[13];

    __syncthreads();

    // ---- Phase 2: per-row compute from/to LDS ----
    if (tid < nrows) {
        const float S1 = lds_y[tid * 5 + 0];
        const float S2 = lds_y[tid * 5 + 1];
        const float S3 = lds_y[tid * 5 + 2];
        const float S4 = lds_y[tid * 5 + 3];
        const float S5 = lds_y[tid * 5 + 4];
        const float P  = lds_c[tid * 3 + 0];
        const float Ep = lds_c[tid * 3 + 1];
        const float T  = lds_c[tid * 3 + 2];

        const float zero = 0.0f;
        const float flux_sf   = fminf(P, fmaxf(zero, P * (tt + 0.5f * tti - T) / tti));
        const float flux_refr = fmaxf(fminf(cfr * cfmax * (ttm - T), S2 / dt), zero);
        const float flux_melt = fmaxf(fminf(cfmax * (T - ttm), S1 / dt), zero);
        const float flux_rf   = fminf(P, fmaxf(zero, P * (T - (tt - 0.5f * tti)) / tti));

        const float r = 0.01f, e = 5.0f;
        const float Smax_raw = whc * S1;
        const float Smax     = fmaxf(Smax_raw, zero);
        const float logistic = 1.0f / (1.0f + expf((S2 - Smax + r * e * Smax) / fmaxf(r, r * Smax)));
        const float flux_in  = (flux_rf + flux_melt) * (1.0f - logistic);
        const float flux_se  = fmaxf((S2 - Smax_raw) / dt, zero);
        const float flux_cf  = fminf(cflux * (1.0f - S3 / fc), S4 / dt);
        const float flux_ea  = fminf(fminf(S3 / (lp * fc) * Ep, Ep), S3 / dt);
        const float flux_r   = (flux_in + flux_se) * powf(fmaxf(S3, zero) / fc, beta);
        const float flux_q0  = fminf(k0 * powf(fmaxf(S4, zero), 1.0f + alpha), fmaxf(S4 / dt, zero));
        const float flux_perc = fminf(perc, S4 / dt);
        const float flux_q1  = k1 * S5;

        lds_d[tid * 5 + 0] = flux_sf + flux_refr - flux_melt;
        lds_d[tid * 5 + 1] = flux_rf + flux_melt - flux_refr - flux_in - flux_se;
        lds_d[tid * 5 + 2] = flux_in + flux_se + flux_cf - flux_ea - flux_r;
        lds_d[tid * 5 + 3] = flux_r - flux_cf - flux_q0 - flux_perc;
        lds_d[tid * 5 + 4] = flux_perc - flux_q1;

        float4* f4 = (float4*)(lds_f + tid * 12);  // 48B stride, 16B aligned
        f4[0] = make_float4(flux_sf, flux_refr, flux_melt, flux_rf);
        f4[1] = make_float4(flux_in, flux_se, flux_cf, flux_ea);
        f4[2] = make_float4(flux_r, flux_q0, flux_perc, flux_q1);
    }

    __syncthreads();

    // ---- Phase 3: coalesced LDS -> global (float4 main, dword tail) ----
    float* __restrict__ db = dS     + (size_t)base * 5u;   // 5120B-aligned
    float* __restrict__ fb = fluxes + (size_t)base * 12u;  // 12288B-aligned
    const int nd = nrows * 5, nf = nrows * 12;
    const int nd4 = nd >> 2, nf4 = nf >> 2;
    for (int k = tid; k < nd4; k += BLOCK)
        ((float4*)db)[k] = ((const float4*)lds_d)[k];
    for (int k = nd4 * 4 + tid; k < nd; k += BLOCK)
        db[k] = lds_d[k];
    for (int k = tid; k < nf4; k += BLOCK)
        ((float4*)fb)[k] = ((const float4*)lds_f)[k];
    for (int k = nf4 * 4 + tid; k < nf; k += BLOCK)
        fb[k] = lds_f[k];
}

extern "C" void kernel_launch(void* const* d_in, const int* in_sizes, int n_in,
                              void* d_out, int out_size, void* d_ws, size_t ws_size,
                              hipStream_t stream) {
    const float* y       = (const float*)d_in[0];
    const float* theta   = (const float*)d_in[1];
    const float* climate = (const float*)d_in[2];
    const float* dt_ptr  = (const float*)d_in[3];
    const int*   t_ptr   = (const int*)d_in[4];

    const int B = in_sizes[0] / 5;

    float* dS     = (float*)d_out;                   // B*5
    float* fluxes = (float*)d_out + (size_t)B * 5u;  // B*12

    const int block = BLOCK;
    const int grid  = (B + block - 1) / block;
    hbv_rhs_kernel<<<grid, block, 0, stream>>>(y, theta, climate, dt_ptr, t_ptr,
                                               dS, fluxes, B);
}